// Round 14
// baseline (67.028 us; speedup 1.0000x reference)
//
#include <hip/hip_runtime.h>
#include <stdint.h>

#define BB 8
#define NN 2048
#define CC 128
#define OO 128

typedef __attribute__((ext_vector_type(8))) short bf16x8;
typedef __attribute__((ext_vector_type(4))) float f32x4;
typedef __attribute__((ext_vector_type(4))) int i32x4;
typedef __attribute__((ext_vector_type(4))) unsigned short u16x4;
typedef unsigned int u32;
typedef unsigned short u16;
typedef unsigned long long u64;

__device__ __forceinline__ u16 f2bf(float f) {
    union { float f; u32 u; } v; v.f = f;
    u32 r = v.u + 0x7FFFu + ((v.u >> 16) & 1u);
    return (u16)(r >> 16);
}

// async global->LDS 16B: LDS dest wave-uniform base + lane*16; swizzle lives
// in the per-lane global source address (m104/m173 rule).
__device__ __forceinline__ void gl_lds16(const u16* g, u16* l) {
    __builtin_amdgcn_global_load_lds(
        (__attribute__((address_space(1))) void*)(uintptr_t)g,
        (__attribute__((address_space(3))) void*)l, 16, 0, 0);
}

// ---------------------------------------------------------------------------
// Kernel B: adj (int32, 134MB) -> bitmask (4MB). Pure sequential stream.
// Wave reads 64 consecutive ints (256B/instr); __ballot packs bit l =
// (adj!=0). LE: u32 word i of the row's bit array covers k in [i*32,i*32+32),
// bit k&31. 2048 blocks x 256 thr = full occupancy stream.
// ---------------------------------------------------------------------------
__global__ __launch_bounds__(256) void bits_kernel(
    const int* __restrict__ adj, u64* __restrict__ bits)
{
    const int l = threadIdx.x & 63;
    const u32 wglob = (blockIdx.x * 256 + threadIdx.x) >> 6;   // 0..8191
    const size_t base = (size_t)wglob * 64;                    // 64 u64 outputs/wave
    #pragma unroll 8
    for (int s = 0; s < 64; ++s) {
        size_t g = base + s;
        int v = adj[g * 64 + l];
        u64 m = __ballot(v != 0);
        if (l == 0) bits[g] = m;
    }
}

// ---------------------------------------------------------------------------
// Kernel 0: Wt[o][c] = bf16(W_lin[c][o]).  (proven R3-R13, verbatim)
// ---------------------------------------------------------------------------
__global__ __launch_bounds__(256) void wt_kernel(
    const float* __restrict__ W_lin, u16* __restrict__ Wt)
{
    __shared__ float ws2[8][132];
    const int t = threadIdx.x, o0 = blockIdx.x * 8;
    f32x4 v = *(const f32x4*)(W_lin + (t >> 1) * OO + o0 + (t & 1) * 4);
    #pragma unroll
    for (int e = 0; e < 4; ++e) ws2[(t & 1) * 4 + e][t >> 1] = v[e];
    __syncthreads();
    const int oo = t >> 5, c0 = (t & 31) * 4;
    f32x4 u = *(const f32x4*)&ws2[oo][c0];
    u16x4 h;
    #pragma unroll
    for (int e = 0; e < 4; ++e) h[e] = f2bf(u[e]);
    *(u16x4*)(Wt + (size_t)(o0 + oo) * CC + c0) = h;
}

// ---------------------------------------------------------------------------
// Kernel 1: precompute via MFMA, no LDS.  (proven R3-R13, verbatim)
// ---------------------------------------------------------------------------
__global__ __launch_bounds__(256) void precompute_kernel(
    const float* __restrict__ x, const float* __restrict__ W_fc,
    const float* __restrict__ b_fc, const u16* __restrict__ Wt,
    float* __restrict__ sj, float* __restrict__ sk, u16* __restrict__ Yt)
{
    const int t = threadIdx.x, l = t & 63, w = t >> 6;
    const int sl = l & 15, g = l >> 4;
    const int b  = blockIdx.x >> 6;
    const int k0 = (blockIdx.x & 63) << 5;
    const int mt = w & 1, nb = (w >> 1) << 2;
    const int row = k0 + mt * 16 + sl;
    const float* xr = x + ((size_t)(b * NN + row) << 7);

    bf16x8 a[4];
    float p1 = 0.f, p2 = 0.f;
    #pragma unroll
    for (int ks = 0; ks < 4; ++ks) {
        f32x4 lo4 = *(const f32x4*)(xr + ks * 32 + g * 8);
        f32x4 hi4 = *(const f32x4*)(xr + ks * 32 + g * 8 + 4);
        f32x4 w1l = *(const f32x4*)(W_fc + ks * 32 + g * 8);
        f32x4 w1h = *(const f32x4*)(W_fc + ks * 32 + g * 8 + 4);
        f32x4 w2l = *(const f32x4*)(W_fc + CC + ks * 32 + g * 8);
        f32x4 w2h = *(const f32x4*)(W_fc + CC + ks * 32 + g * 8 + 4);
        bf16x8 av;
        #pragma unroll
        for (int e = 0; e < 4; ++e) {
            p1 += lo4[e] * w1l[e] + hi4[e] * w1h[e];
            p2 += lo4[e] * w2l[e] + hi4[e] * w2h[e];
            av[e]     = (short)f2bf(lo4[e]);
            av[e + 4] = (short)f2bf(hi4[e]);
        }
        a[ks] = av;
    }
    p1 += __shfl_xor(p1, 16); p1 += __shfl_xor(p1, 32);
    p2 += __shfl_xor(p2, 16); p2 += __shfl_xor(p2, 32);
    if (w < 2 && g == 0) {
        sj[b * NN + row] = p1 + b_fc[0];
        sk[b * NN + row] = p2;
    }

    f32x4 acc[4];
    #pragma unroll
    for (int i = 0; i < 4; ++i) acc[i] = (f32x4){0.f, 0.f, 0.f, 0.f};
    #pragma unroll
    for (int i = 0; i < 4; ++i) {
        const u16* wp = Wt + (size_t)((nb + i) * 16 + sl) * CC;
        #pragma unroll
        for (int ks = 0; ks < 4; ++ks) {
            bf16x8 bv = *(const bf16x8*)(wp + ks * 32 + g * 8);
            acc[i] = __builtin_amdgcn_mfma_f32_16x16x32_bf16(a[ks], bv, acc[i], 0, 0, 0);
        }
    }
    #pragma unroll
    for (int i = 0; i < 4; ++i) {
        const int o = (nb + i) * 16 + sl;
        u16x4 h;
        #pragma unroll
        for (int e = 0; e < 4; ++e) h[e] = f2bf(acc[i][e]);
        *(u16x4*)(Yt + (size_t)(b * OO + o) * NN + k0 + mt * 16 + g * 4) = h;
    }
}

// ---------------------------------------------------------------------------
// Kernel 2: main fused aggregation = R11's PASSING kernel VERBATIM, with the
// ONLY change being adj reads -> bitmask reads:
//   - per tile, thread loads 4 u32 (one per row q) instead of 4 i32x4:
//     word = bits32[row_base + lo>>3 + kt*4]; predicate bit = (lo&7)*4 + e.
//     Identical predicate (adj!=0), identical sigmoid/psum/pbuf math.
//   - VMEM/iter stays 13 (8 stage + 4 adj-u32 + 1 sk) -> vmcnt(18) and the
//     2-deep rotation prefetch carry over UNCHANGED.
// adj in-loop HBM traffic: 134MB -> 4MB (the R13-profile-identified bottleneck).
// 512 blocks (b = bid&7 XCD-pinned), 4 waves, LDS 72.5KB, 2 blocks/CU.
// ---------------------------------------------------------------------------
__global__ __launch_bounds__(256, 2) void graphconv_main(
    const u32* __restrict__ bits32, const float* __restrict__ sj,
    const float* __restrict__ sk, const u16* __restrict__ Yt,
    const float* __restrict__ b_lin, float* __restrict__ out)
{
    __shared__ __align__(16) u16 ybuf[2][16384];  // 2 x (128 o x 16 chunks x 8)
    __shared__ __align__(16) u16 pbuf[4096];      // 32 j x 16 chunks x 8
    __shared__ float Sld[32];

    const int t  = threadIdx.x;
    const int l  = t & 63, w = t >> 6;
    const int sw = l & 15, kg = l >> 4;
    const int lo = l & 31, hi = l >> 5;
    const int b  = blockIdx.x & 7;
    const int j0 = (blockIdx.x >> 3) << 5;

    // P-phase mapping (R3/R11): instr q covers rows w*8+2q+hi, k = lo*4+e
    const u32* brow[4];
    float sjr[4];
    #pragma unroll
    for (int q = 0; q < 4; ++q) {
        const int R = j0 + w * 8 + 2 * q + hi;
        brow[q] = bits32 + ((size_t)b * NN + R) * 64 + (lo >> 3);
        sjr[q]  = sj[b * NN + R];
    }
    const int nsh = (lo & 7) * 4;             // nibble shift within the u32
    const float* skp = sk + b * NN + lo * 4;

    // Y staging (VERBATIM R11): linear LDS dest, inverse-swizzled global src
    u32 yoff[8];
    #pragma unroll
    for (int i = 0; i < 8; ++i) {
        int u  = (w * 8 + i) * 64 + l;
        int o  = u >> 4;
        int kc = (u & 15) ^ (o & 15);
        yoff[i] = (u32)(b * OO + o) * NN + kc * 8;
    }

    f32x4 acc[2][2];
    #pragma unroll
    for (int js = 0; js < 2; ++js)
        #pragma unroll
        for (int os = 0; os < 2; ++os) acc[js][os] = (f32x4){0.f, 0.f, 0.f, 0.f};
    float psum[4] = {0.f, 0.f, 0.f, 0.f};

    // prologue: stage(0) [8] + bits/sk(0) [5] + bits/sk(1) [5]
    #pragma unroll
    for (int i = 0; i < 8; ++i)
        gl_lds16(Yt + yoff[i], &ybuf[0][(w * 8 + i) * 512]);
    u32 a_cur[4], a_n1[4];
    f32x4 s_cur, s_n1;
    #pragma unroll
    for (int q = 0; q < 4; ++q) a_cur[q] = brow[q][0];
    s_cur = *(const f32x4*)(skp);
    #pragma unroll
    for (int q = 0; q < 4; ++q) a_n1[q] = brow[q][4];
    s_n1 = *(const f32x4*)(skp + 128);

    for (int kt = 0; kt < 16; ++kt) {
        const int cur = kt & 1;
        const int kt1 = (kt < 15) ? kt + 1 : 15;  // tail re-stage: idempotent
        const int kt2 = (kt < 14) ? kt + 2 : 15;  // keeps vmcnt count uniform
        // stage next Y tile (in flight across this whole iteration)
        #pragma unroll
        for (int i = 0; i < 8; ++i)
            gl_lds16(Yt + yoff[i] + (kt1 << 7), &ybuf[cur ^ 1][(w * 8 + i) * 512]);
        // 2-deep bits/sk prefetch
        u32 a_n2[4]; f32x4 s_n2;
        #pragma unroll
        for (int q = 0; q < 4; ++q) a_n2[q] = brow[q][kt2 * 4];
        s_n2 = *(const f32x4*)(skp + kt2 * 128);

        // P = masked sigmoid; per-thread rowsum accumulates in registers
        u16x4 hq[4];
        #pragma unroll
        for (int q = 0; q < 4; ++q) {
            #pragma unroll
            for (int e = 0; e < 4; ++e) {
                float z  = sjr[q] + s_cur[e];
                float sg = __builtin_amdgcn_rcpf(1.0f + __expf(-z));
                float pv = ((a_cur[q] >> (nsh + e)) & 1u) ? sg : 0.0f;
                psum[q] += pv;
                hq[q][e] = f2bf(pv);
            }
        }
        {
            const int kc = lo >> 1, hh = lo & 1;
            #pragma unroll
            for (int q = 0; q < 4; ++q) {
                const int R = w * 8 + 2 * q + hi;
                const int u = R * 16 + (kc ^ (R & 15));
                *(u16x4*)&pbuf[u * 8 + hh * 4] = hq[q];
            }
        }

        // counted drain: stage(kt) complete, 18 younger ops stay in flight
        asm volatile("s_waitcnt vmcnt(18)" ::: "memory");
        asm volatile("s_waitcnt lgkmcnt(0)" ::: "memory");
        __builtin_amdgcn_s_barrier();
        asm volatile("" ::: "memory");

        // MFMA: wave w -> j 0..31 x o [w*32, w*32+32)
        #pragma unroll
        for (int kk = 0; kk < 4; ++kk) {
            const int kc = kk * 4 + kg;
            bf16x8 af[2], bfr[2];
            #pragma unroll
            for (int js = 0; js < 2; ++js)
                af[js] = *(const bf16x8*)&pbuf[((js * 16 + sw) * 16 + (kc ^ sw)) * 8];
            #pragma unroll
            for (int os = 0; os < 2; ++os) {
                int o = w * 32 + os * 16 + sw;
                bfr[os] = *(const bf16x8*)&ybuf[cur][(o * 16 + (kc ^ sw)) * 8];
            }
            #pragma unroll
            for (int js = 0; js < 2; ++js)
                #pragma unroll
                for (int os = 0; os < 2; ++os)
                    acc[js][os] = __builtin_amdgcn_mfma_f32_16x16x32_bf16(
                        af[js], bfr[os], acc[js][os], 0, 0, 0);
        }

        asm volatile("" ::: "memory");
        __builtin_amdgcn_s_barrier();   // MFMA LDS reads done before next writes
        asm volatile("" ::: "memory");

        #pragma unroll
        for (int q = 0; q < 4; ++q) a_cur[q] = a_n1[q];
        s_cur = s_n1;
        #pragma unroll
        for (int q = 0; q < 4; ++q) a_n1[q] = a_n2[q];
        s_n1 = s_n2;
    }

    // rowsum reduce (VERBATIM R11): rows' 128 k live across 32 lanes (same hi)
    #pragma unroll
    for (int q = 0; q < 4; ++q) {
        float s = psum[q];
        s += __shfl_xor(s, 1); s += __shfl_xor(s, 2); s += __shfl_xor(s, 4);
        s += __shfl_xor(s, 8); s += __shfl_xor(s, 16);
        if (lo == 0) Sld[w * 8 + 2 * q + hi] = s;
    }
    __syncthreads();   // also drains tail junk DMA (vmcnt 0) before LDS reuse ends

    #pragma unroll
    for (int js = 0; js < 2; ++js) {
        float rinv[4];
        #pragma unroll
        for (int i = 0; i < 4; ++i) rinv[i] = 1.0f / Sld[js * 16 + kg * 4 + i];
        #pragma unroll
        for (int os = 0; os < 2; ++os) {
            const int col = w * 32 + os * 16 + sw;
            const float bl = b_lin[col];
            #pragma unroll
            for (int i = 0; i < 4; ++i) {
                size_t row = (size_t)(b * NN + j0 + js * 16 + kg * 4 + i);
                out[row * OO + col] = acc[js][os][i] * rinv[i] + bl;
            }
        }
    }
}

extern "C" void kernel_launch(void* const* d_in, const int* in_sizes, int n_in,
                              void* d_out, int out_size, void* d_ws, size_t ws_size,
                              hipStream_t stream) {
    const float* x     = (const float*)d_in[0];
    const int*   adj   = (const int*)d_in[1];
    const float* W_fc  = (const float*)d_in[2];
    const float* b_fc  = (const float*)d_in[3];
    const float* W_lin = (const float*)d_in[4];
    const float* b_lin = (const float*)d_in[5];
    float* out = (float*)d_out;

    // workspace: Yt 4MB | sj 64KB | sk 64KB | Wt 32KB | bits 4MB (~8.4MB)
    u16*   Yt = (u16*)d_ws;
    float* sj = (float*)((char*)d_ws + (size_t)BB * OO * NN * sizeof(u16));
    float* sk = sj + BB * NN;
    u16*   Wt = (u16*)(sk + BB * NN);
    u64*   bits = (u64*)((char*)d_ws + 4ull * 1024 * 1024 + 256 * 1024);

    bits_kernel<<<2048, 256, 0, stream>>>(adj, bits);
    wt_kernel<<<16, 256, 0, stream>>>(W_lin, Wt);
    precompute_kernel<<<512, 256, 0, stream>>>(x, W_fc, b_fc, Wt, sj, sk, Yt);
    graphconv_main<<<512, 256, 0, stream>>>((const u32*)bits, sj, sk, Yt, b_lin, out);
}

// Round 15
// 48.492 us; speedup vs baseline: 1.3822x; 1.3822x over previous
//
#include <hip/hip_runtime.h>
#include <stdint.h>

#define BB 8
#define NN 2048
#define CC 128
#define OO 128

typedef __attribute__((ext_vector_type(8))) short bf16x8;
typedef __attribute__((ext_vector_type(4))) float f32x4;
typedef __attribute__((ext_vector_type(4))) int i32x4;
typedef __attribute__((ext_vector_type(4))) unsigned short u16x4;
typedef unsigned int u32;
typedef unsigned short u16;

__device__ __forceinline__ u16 f2bf(float f) {
    union { float f; u32 u; } v; v.f = f;
    u32 r = v.u + 0x7FFFu + ((v.u >> 16) & 1u);
    return (u16)(r >> 16);
}

// async global->LDS 16B: LDS dest wave-uniform base + lane*16; swizzle lives
// in the per-lane global source address (m104/m173 rule).
__device__ __forceinline__ void gl_lds16(const u16* g, u16* l) {
    __builtin_amdgcn_global_load_lds(
        (__attribute__((address_space(1))) void*)(uintptr_t)g,
        (__attribute__((address_space(3))) void*)l, 16, 0, 0);
}

// ---------------------------------------------------------------------------
// Kernel 0: Wt[o][c] = bf16(W_lin[c][o]).  (proven R3-R14, verbatim)
// ---------------------------------------------------------------------------
__global__ __launch_bounds__(256) void wt_kernel(
    const float* __restrict__ W_lin, u16* __restrict__ Wt)
{
    __shared__ float ws2[8][132];
    const int t = threadIdx.x, o0 = blockIdx.x * 8;
    f32x4 v = *(const f32x4*)(W_lin + (t >> 1) * OO + o0 + (t & 1) * 4);
    #pragma unroll
    for (int e = 0; e < 4; ++e) ws2[(t & 1) * 4 + e][t >> 1] = v[e];
    __syncthreads();
    const int oo = t >> 5, c0 = (t & 31) * 4;
    f32x4 u = *(const f32x4*)&ws2[oo][c0];
    u16x4 h;
    #pragma unroll
    for (int e = 0; e < 4; ++e) h[e] = f2bf(u[e]);
    *(u16x4*)(Wt + (size_t)(o0 + oo) * CC + c0) = h;
}

// ---------------------------------------------------------------------------
// Kernel 1: precompute via MFMA, no LDS.  (proven R3-R14, verbatim)
// ---------------------------------------------------------------------------
__global__ __launch_bounds__(256) void precompute_kernel(
    const float* __restrict__ x, const float* __restrict__ W_fc,
    const float* __restrict__ b_fc, const u16* __restrict__ Wt,
    float* __restrict__ sj, float* __restrict__ sk, u16* __restrict__ Yt)
{
    const int t = threadIdx.x, l = t & 63, w = t >> 6;
    const int sl = l & 15, g = l >> 4;
    const int b  = blockIdx.x >> 6;
    const int k0 = (blockIdx.x & 63) << 5;
    const int mt = w & 1, nb = (w >> 1) << 2;
    const int row = k0 + mt * 16 + sl;
    const float* xr = x + ((size_t)(b * NN + row) << 7);

    bf16x8 a[4];
    float p1 = 0.f, p2 = 0.f;
    #pragma unroll
    for (int ks = 0; ks < 4; ++ks) {
        f32x4 lo4 = *(const f32x4*)(xr + ks * 32 + g * 8);
        f32x4 hi4 = *(const f32x4*)(xr + ks * 32 + g * 8 + 4);
        f32x4 w1l = *(const f32x4*)(W_fc + ks * 32 + g * 8);
        f32x4 w1h = *(const f32x4*)(W_fc + ks * 32 + g * 8 + 4);
        f32x4 w2l = *(const f32x4*)(W_fc + CC + ks * 32 + g * 8);
        f32x4 w2h = *(const f32x4*)(W_fc + CC + ks * 32 + g * 8 + 4);
        bf16x8 av;
        #pragma unroll
        for (int e = 0; e < 4; ++e) {
            p1 += lo4[e] * w1l[e] + hi4[e] * w1h[e];
            p2 += lo4[e] * w2l[e] + hi4[e] * w2h[e];
            av[e]     = (short)f2bf(lo4[e]);
            av[e + 4] = (short)f2bf(hi4[e]);
        }
        a[ks] = av;
    }
    p1 += __shfl_xor(p1, 16); p1 += __shfl_xor(p1, 32);
    p2 += __shfl_xor(p2, 16); p2 += __shfl_xor(p2, 32);
    if (w < 2 && g == 0) {
        sj[b * NN + row] = p1 + b_fc[0];
        sk[b * NN + row] = p2;
    }

    f32x4 acc[4];
    #pragma unroll
    for (int i = 0; i < 4; ++i) acc[i] = (f32x4){0.f, 0.f, 0.f, 0.f};
    #pragma unroll
    for (int i = 0; i < 4; ++i) {
        const u16* wp = Wt + (size_t)((nb + i) * 16 + sl) * CC;
        #pragma unroll
        for (int ks = 0; ks < 4; ++ks) {
            bf16x8 bv = *(const bf16x8*)(wp + ks * 32 + g * 8);
            acc[i] = __builtin_amdgcn_mfma_f32_16x16x32_bf16(a[ks], bv, acc[i], 0, 0, 0);
        }
    }
    #pragma unroll
    for (int i = 0; i < 4; ++i) {
        const int o = (nb + i) * 16 + sl;
        u16x4 h;
        #pragma unroll
        for (int e = 0; e < 4; ++e) h[e] = f2bf(acc[i][e]);
        *(u16x4*)(Yt + (size_t)(b * OO + o) * NN + k0 + mt * 16 + g * 4) = h;
    }
}

// ---------------------------------------------------------------------------
// Kernel 2: main — R13's single-barrier pipelined kernel (PASSED correctness)
// with ONE change: Sld aliased into pbuf[0] -> LDS = 81920B EXACTLY (was
// 82048 -> 82432 alloc -> 1 blk/CU; R13's counter showed the occupancy loss).
// Now 2 blocks/CU. Alias safety: pbuf[0]'s last reader is MFMA(14) (body 14,
// fenced by its ending barrier); peeled tile 15 reads only pbuf[1]/ybuf[1];
// vmcnt(0) before the peel drains all DMA; final __syncthreads() before
// epilogue reads Sld.
// ---------------------------------------------------------------------------
__global__ __launch_bounds__(256, 2) void graphconv_main(
    const int* __restrict__ adj, const float* __restrict__ sj,
    const float* __restrict__ sk, const u16* __restrict__ Yt,
    const float* __restrict__ b_lin, float* __restrict__ out)
{
    __shared__ __align__(16) u16 ybuf[2][16384];  // [par][128 o x 16 chunks x 8]
    __shared__ __align__(16) u16 pbuf[2][4096];   // [par][32 j x 16 chunks x 8]
    float* Sld = (float*)&pbuf[0][0];             // alias; used only post-loop

    const int t  = threadIdx.x;
    const int l  = t & 63, w = t >> 6;
    const int sw = l & 15, kg = l >> 4;
    const int lo = l & 31, hi = l >> 5;
    const int b  = blockIdx.x & 7;
    const int j0 = (blockIdx.x >> 3) << 5;

    // P-phase mapping (VERBATIM R3): instr q covers rows w*8+2q+hi, 16B/lane
    const int* arow[4];
    float sjr[4];
    #pragma unroll
    for (int q = 0; q < 4; ++q) {
        const int R = j0 + w * 8 + 2 * q + hi;
        arow[q] = adj + ((size_t)b * NN + R) * NN + lo * 4;
        sjr[q]  = sj[b * NN + R];
    }
    const float* skp = sk + b * NN + lo * 4;

    // Y staging (VERBATIM R3): linear LDS dest, inverse-swizzled global src
    u32 yoff[8];
    #pragma unroll
    for (int i = 0; i < 8; ++i) {
        int u  = (w * 8 + i) * 64 + l;
        int o  = u >> 4;
        int kc = (u & 15) ^ (o & 15);
        yoff[i] = (u32)(b * OO + o) * NN + kc * 8;
    }

    f32x4 acc[2][2];
    #pragma unroll
    for (int js = 0; js < 2; ++js)
        #pragma unroll
        for (int os = 0; os < 2; ++os) acc[js][os] = (f32x4){0.f, 0.f, 0.f, 0.f};
    float psum[4] = {0.f, 0.f, 0.f, 0.f};

// sigmoid for one tile from (AV,SV) -> pbuf[PAR] (R3-proven arithmetic/mapping)
#define SIGP(AV, SV, PAR)                                                     \
    {                                                                         \
        u16x4 hq[4];                                                          \
        _Pragma("unroll")                                                     \
        for (int q = 0; q < 4; ++q) {                                         \
            _Pragma("unroll")                                                 \
            for (int e = 0; e < 4; ++e) {                                     \
                float z  = sjr[q] + SV[e];                                    \
                float sg = __builtin_amdgcn_rcpf(1.0f + __expf(-z));          \
                float pv = AV[q][e] ? sg : 0.0f;                              \
                psum[q] += pv;                                                \
                hq[q][e] = f2bf(pv);                                          \
            }                                                                 \
        }                                                                     \
        const int kc_ = lo >> 1, hh_ = lo & 1;                                \
        _Pragma("unroll")                                                     \
        for (int q = 0; q < 4; ++q) {                                         \
            const int R = w * 8 + 2 * q + hi;                                 \
            const int u = R * 16 + (kc_ ^ (R & 15));                          \
            *(u16x4*)&pbuf[PAR][u * 8 + hh_ * 4] = hq[q];                     \
        }                                                                     \
    }

    // prologue: stage(0); adj/sk(0) temp; E<-adj/sk(1); O<-adj/sk(2);
    // sigmoid(0)->pbuf[0]; lgkm+barrier. (body 0's vmcnt(18) covers ybuf[0])
    #pragma unroll
    for (int i = 0; i < 8; ++i)
        gl_lds16(Yt + yoff[i], &ybuf[0][(w * 8 + i) * 512]);
    i32x4 aT[4], aE[4], aO[4];
    f32x4 sT, sE, sO;
    #pragma unroll
    for (int q = 0; q < 4; ++q) aT[q] = *(const i32x4*)(arow[q]);
    sT = *(const f32x4*)(skp);
    #pragma unroll
    for (int q = 0; q < 4; ++q) aE[q] = *(const i32x4*)(arow[q] + 128);
    sE = *(const f32x4*)(skp + 128);
    #pragma unroll
    for (int q = 0; q < 4; ++q) aO[q] = *(const i32x4*)(arow[q] + 256);
    sO = *(const f32x4*)(skp + 256);
    SIGP(aT, sT, 0)                       // auto-wait drains stage(0)+aT
    asm volatile("s_waitcnt lgkmcnt(0)" ::: "memory");
    __builtin_amdgcn_s_barrier();
    asm volatile("" ::: "memory");

// body T (0..14): stage(T+1); sigmoid(T+1) from AC/SC (loaded 2 bodies ago);
// reload AC/SC <- adj/sk(min(T+3,15)); vmcnt(18) [stage(T) retired]; MFMA(T);
// lgkm+barrier.
#define TILE_BODY(T, AC, SC)                                                  \
    {                                                                         \
        const int T_ = (T);                                                   \
        const int tn = T_ + 1;                                                \
        const int tp = (T_ + 3 > 15) ? 15 : T_ + 3;                           \
        const int pn = tn & 1, pc = T_ & 1;                                   \
        _Pragma("unroll")                                                     \
        for (int i = 0; i < 8; ++i)                                           \
            gl_lds16(Yt + yoff[i] + (tn << 7), &ybuf[pn][(w * 8 + i) * 512]); \
        SIGP(AC, SC, pn)                                                      \
        _Pragma("unroll")                                                     \
        for (int q = 0; q < 4; ++q)                                           \
            AC[q] = *(const i32x4*)(arow[q] + tp * 128);                      \
        SC = *(const f32x4*)(skp + tp * 128);                                 \
        asm volatile("s_waitcnt vmcnt(18)" ::: "memory");                     \
        _Pragma("unroll")                                                     \
        for (int kk = 0; kk < 4; ++kk) {                                      \
            const int kc = kk * 4 + kg;                                       \
            bf16x8 af[2], bfr[2];                                             \
            _Pragma("unroll")                                                 \
            for (int js = 0; js < 2; ++js)                                    \
                af[js] = *(const bf16x8*)&pbuf[pc][((js * 16 + sw) * 16 + (kc ^ sw)) * 8]; \
            _Pragma("unroll")                                                 \
            for (int os = 0; os < 2; ++os) {                                  \
                int o = w * 32 + os * 16 + sw;                                \
                bfr[os] = *(const bf16x8*)&ybuf[pc][(o * 16 + (kc ^ sw)) * 8]; \
            }                                                                 \
            _Pragma("unroll")                                                 \
            for (int js = 0; js < 2; ++js)                                    \
                _Pragma("unroll")                                             \
                for (int os = 0; os < 2; ++os)                                \
                    acc[js][os] = __builtin_amdgcn_mfma_f32_16x16x32_bf16(    \
                        af[js], bfr[os], acc[js][os], 0, 0, 0);               \
        }                                                                     \
        asm volatile("s_waitcnt lgkmcnt(0)" ::: "memory");                    \
        __builtin_amdgcn_s_barrier();                                         \
        asm volatile("" ::: "memory");                                        \
    }

    for (int m = 0; m < 7; ++m) {
        TILE_BODY(2 * m,     aE, sE)      // consumes adj(2m+1), reloads (2m+3)
        TILE_BODY(2 * m + 1, aO, sO)      // consumes adj(2m+2), reloads (2m+4)
    }
    TILE_BODY(14, aE, sE)                 // consumes adj(15), reloads junk
#undef TILE_BODY
#undef SIGP

    // peeled tile 15: pbuf[1]/ybuf[1] (written body 14; visible after barrier)
    asm volatile("s_waitcnt vmcnt(0)" ::: "memory");   // stage(15) certainly done
    #pragma unroll
    for (int kk = 0; kk < 4; ++kk) {
        const int kc = kk * 4 + kg;
        bf16x8 af[2], bfr[2];
        #pragma unroll
        for (int js = 0; js < 2; ++js)
            af[js] = *(const bf16x8*)&pbuf[1][((js * 16 + sw) * 16 + (kc ^ sw)) * 8];
        #pragma unroll
        for (int os = 0; os < 2; ++os) {
            int o = w * 32 + os * 16 + sw;
            bfr[os] = *(const bf16x8*)&ybuf[1][(o * 16 + (kc ^ sw)) * 8];
        }
        #pragma unroll
        for (int js = 0; js < 2; ++js)
            #pragma unroll
            for (int os = 0; os < 2; ++os)
                acc[js][os] = __builtin_amdgcn_mfma_f32_16x16x32_bf16(
                    af[js], bfr[os], acc[js][os], 0, 0, 0);
    }

    // rowsum reduce (VERBATIM R3); Sld = pbuf[0] alias (pbuf[0] dead since
    // body 14's ending barrier — only pbuf[1] was read by the peel)
    #pragma unroll
    for (int q = 0; q < 4; ++q) {
        float s = psum[q];
        s += __shfl_xor(s, 1); s += __shfl_xor(s, 2); s += __shfl_xor(s, 4);
        s += __shfl_xor(s, 8); s += __shfl_xor(s, 16);
        if (lo == 0) Sld[w * 8 + 2 * q + hi] = s;
    }
    __syncthreads();

    // epilogue (VERBATIM R3)
    #pragma unroll
    for (int js = 0; js < 2; ++js) {
        float rinv[4];
        #pragma unroll
        for (int i = 0; i < 4; ++i) rinv[i] = 1.0f / Sld[js * 16 + kg * 4 + i];
        #pragma unroll
        for (int os = 0; os < 2; ++os) {
            const int col = w * 32 + os * 16 + sw;
            const float bl = b_lin[col];
            #pragma unroll
            for (int i = 0; i < 4; ++i) {
                size_t row = (size_t)(b * NN + j0 + js * 16 + kg * 4 + i);
                out[row * OO + col] = acc[js][os][i] * rinv[i] + bl;
            }
        }
    }
}

extern "C" void kernel_launch(void* const* d_in, const int* in_sizes, int n_in,
                              void* d_out, int out_size, void* d_ws, size_t ws_size,
                              hipStream_t stream) {
    const float* x     = (const float*)d_in[0];
    const int*   adj   = (const int*)d_in[1];
    const float* W_fc  = (const float*)d_in[2];
    const float* b_fc  = (const float*)d_in[3];
    const float* W_lin = (const float*)d_in[4];
    const float* b_lin = (const float*)d_in[5];
    float* out = (float*)d_out;

    // workspace: Yt (bf16, 4MB) | sj (64KB) | sk (64KB) | Wt (32KB)  (proven)
    u16*   Yt = (u16*)d_ws;
    float* sj = (float*)((char*)d_ws + (size_t)BB * OO * NN * sizeof(u16));
    float* sk = sj + BB * NN;
    u16*   Wt = (u16*)(sk + BB * NN);

    wt_kernel<<<16, 256, 0, stream>>>(W_lin, Wt);
    precompute_kernel<<<512, 256, 0, stream>>>(x, W_fc, b_fc, Wt, sj, sk, Yt);
    graphconv_main<<<512, 256, 0, stream>>>(adj, sj, sk, Yt, b_lin, out);
}